// Round 3
// baseline (1447.933 us; speedup 1.0000x reference)
//
#include <hip/hip_runtime.h>
#include <hip/hip_bf16.h>
#include <math.h>

#define SEQ   2048
#define HDIM  1024
#define NH    16
#define NKV   4
#define DHEAD 64
#define TOPK  128
#define GROUPS 4

// ---------------- f32 tiled GEMM: C[M,N] = A[M,K] @ W[N,K]^T + bias ----------
__global__ __launch_bounds__(256) void gemm_f32(
    const float* __restrict__ A, const float* __restrict__ W,
    const float* __restrict__ bias, float* __restrict__ C,
    int M, int N, int K) {
  constexpr int BM = 64, BN = 64, BK = 16;
  __shared__ float As[BK][BM + 1];
  __shared__ float Ws[BK][BN + 1];
  int tid = threadIdx.x;
  int tx = tid & 15, ty = tid >> 4;
  int lr = tid >> 4, lc = tid & 15;
  int m0 = blockIdx.y * BM, n0 = blockIdx.x * BN;
  float acc[4][4] = {};
  for (int k0 = 0; k0 < K; k0 += BK) {
#pragma unroll
    for (int i = 0; i < 4; ++i) {
      int ar = m0 + lr + 16 * i;           // M==2048, always in-bounds
      As[lc][lr + 16 * i] = A[(long)ar * K + k0 + lc];
      int wr = n0 + lr + 16 * i;
      Ws[lc][lr + 16 * i] = (wr < N) ? W[(long)wr * K + k0 + lc] : 0.f;
    }
    __syncthreads();
#pragma unroll
    for (int kk = 0; kk < BK; ++kk) {
      float a[4], b[4];
#pragma unroll
      for (int i = 0; i < 4; ++i) a[i] = As[kk][ty * 4 + i];
#pragma unroll
      for (int j = 0; j < 4; ++j) b[j] = Ws[kk][tx * 4 + j];
#pragma unroll
      for (int i = 0; i < 4; ++i)
#pragma unroll
        for (int j = 0; j < 4; ++j) acc[i][j] += a[i] * b[j];
    }
    __syncthreads();
  }
#pragma unroll
  for (int i = 0; i < 4; ++i) {
    int m = m0 + ty * 4 + i;
#pragma unroll
    for (int j = 0; j < 4; ++j) {
      int n = n0 + tx * 4 + j;
      if (n < N) C[(long)m * N + n] = acc[i][j] + (bias ? bias[n] : 0.f);
    }
  }
}

// ---------------- RoPE in place on q (S,NH,D), k (S,NKV,D), ik (S,D) --------
__global__ void rope_kernel(float* __restrict__ q, float* __restrict__ k,
                            float* __restrict__ ik,
                            const float* __restrict__ cosb,
                            const float* __restrict__ sinb) {
  int gid = blockIdx.x * 256 + threadIdx.x;
  const int NV = SEQ * (NH + NKV + 1);
  if (gid >= NV * 32) return;
  int p = gid & 31;
  int vec = gid >> 5;
  float* base;
  int s;
  if (vec < SEQ * NH) {
    s = vec / NH; int h = vec % NH;
    base = q + (long)s * 1024 + h * 64;
  } else if (vec < SEQ * (NH + NKV)) {
    int t = vec - SEQ * NH;
    s = t / NKV; int kh = t % NKV;
    base = k + (long)s * 256 + kh * 64;
  } else {
    s = vec - SEQ * (NH + NKV);
    base = ik + (long)s * 64;
  }
  float c = cosb[s * 64 + p], sn = sinb[s * 64 + p];
  float x1 = base[p], x2 = base[p + 32];
  base[p]      = x1 * c - x2 * sn;
  base[p + 32] = x2 * c + x1 * sn;
}

// ---------------- indexer scores + exact top-128 per query row --------------
__device__ inline unsigned fkey(float f) {
  unsigned u = __float_as_uint(f);
  return (u & 0x80000000u) ? ~u : (u | 0x80000000u);
}

__global__ __launch_bounds__(256) void indexer_topk(
    const float* __restrict__ qb, const float* __restrict__ ikb,
    const float* __restrict__ wb, int* __restrict__ tidx,
    int* __restrict__ tcnt) {
  int qi = blockIdx.x;
  int tid = threadIdx.x;
  if (qi < TOPK) {                 // row length <= 128: all causal positions
    for (int i = tid; i <= qi; i += 256) tidx[qi * TOPK + i] = i;
    if (tid == 0) tcnt[qi] = qi + 1;
    return;
  }
  __shared__ float qls[NH * DHEAD];
  __shared__ float wls[NH];
  __shared__ float sc[SEQ];
  __shared__ float ikt[128][DHEAD + 1];
  __shared__ int red;
  __shared__ int c1;
#pragma unroll
  for (int i = 0; i < 4; ++i)
    qls[tid + i * 256] = qb[(long)qi * 1024 + tid + i * 256];
  if (tid < NH) wls[tid] = wb[qi * NH + tid] * 0.25f;  // * NH^-0.5
  for (int i = tid; i < SEQ; i += 256) sc[i] = -INFINITY;
  __syncthreads();
  int r = tid & 127, half = tid >> 7;
  for (int k0 = 0; k0 <= qi; k0 += 128) {
#pragma unroll
    for (int i = 0; i < 32; ++i) {
      int f = tid + i * 256;
      int rr = f >> 6, cc = f & 63;
      int krow = k0 + rr;
      ikt[rr][cc] = (krow < SEQ) ? ikb[(long)krow * 64 + cc] : 0.f;
    }
    __syncthreads();
    int k = k0 + r;
    float acc = 0.f;
    if (k <= qi) {
#pragma unroll
      for (int hh = 0; hh < 8; ++hh) {
        int h = half * 8 + hh;
        float dot = 0.f;
#pragma unroll
        for (int d = 0; d < DHEAD; ++d) dot += qls[h * 64 + d] * ikt[r][d];
        acc += fmaxf(dot, 0.f) * wls[h];
      }
      if (half == 0) sc[k] = acc;
    }
    __syncthreads();
    if (k <= qi && half == 1) sc[k] = (sc[k] + acc) + 0.f;  // +0: kill -0.0
    __syncthreads();
  }
  unsigned keys[8];
#pragma unroll
  for (int i = 0; i < 8; ++i) keys[i] = fkey(sc[tid + i * 256]);
  // binary search: max T with count(key >= T) >= TOPK
  unsigned lo = 0u, hi = 0xFFFFFFFEu;
  while (lo < hi) {
    unsigned mid = lo + ((hi - lo + 1) >> 1);
    if (tid == 0) red = 0;
    __syncthreads();
    int local = 0;
#pragma unroll
    for (int i = 0; i < 8; ++i) local += (keys[i] >= mid) ? 1 : 0;
    for (int off = 32; off; off >>= 1) local += __shfl_down(local, off);
    if ((tid & 63) == 0) atomicAdd(&red, local);
    __syncthreads();
    int c = red;
    __syncthreads();
    if (c >= TOPK) lo = mid; else hi = mid - 1;
  }
  unsigned T = lo;
  if (tid == 0) c1 = 0;
  __syncthreads();
#pragma unroll
  for (int i = 0; i < 8; ++i) {
    int k = tid + i * 256;
    if (k <= qi && keys[i] > T) {
      int pos = atomicAdd(&c1, 1);
      tidx[qi * TOPK + pos] = k;
    }
  }
  __syncthreads();
  if (tid == 0) {
    int c = c1;
    for (int k = 0; k <= qi && c < TOPK; ++k)
      if (fkey(sc[k]) == T) tidx[qi * TOPK + c++] = k;
    tcnt[qi] = TOPK;
  }
}

// ---------------- sparse attention over selected keys, one wave per (q,h) ---
__global__ __launch_bounds__(64) void sparse_attn(
    const float* __restrict__ qb, const float* __restrict__ kb,
    const float* __restrict__ vb, const int* __restrict__ tidx,
    const int* __restrict__ tcnt, float* __restrict__ attn) {
  int h = blockIdx.x;
  int qi = blockIdx.y;
  int lane = threadIdx.x;
  int kvh = h >> 2;                       // GROUPS=4
  int cnt = tcnt[qi];
  const int* idx = tidx + qi * TOPK;
  __shared__ float qsh[DHEAD];
  qsh[lane] = qb[(long)qi * 1024 + h * 64 + lane];
  __syncthreads();
  float l0 = -INFINITY, l1 = -INFINITY;
#pragma unroll
  for (int slot = 0; slot < 2; ++slot) {
    int j = lane + slot * 64;
    if (j < cnt) {
      int ki = idx[j];
      const float4* k4 = (const float4*)(kb + (long)ki * 256 + kvh * 64);
      float dot = 0.f;
#pragma unroll
      for (int d4 = 0; d4 < 16; ++d4) {
        float4 kk = k4[d4];
        dot += qsh[d4 * 4 + 0] * kk.x + qsh[d4 * 4 + 1] * kk.y +
               qsh[d4 * 4 + 2] * kk.z + qsh[d4 * 4 + 3] * kk.w;
      }
      float l = dot * 0.125f;             // D^-0.5
      if (slot == 0) l0 = l; else l1 = l;
    }
  }
  float m = fmaxf(l0, l1);
  for (int off = 32; off; off >>= 1) m = fmaxf(m, __shfl_xor(m, off));
  float p0 = expf(l0 - m), p1 = expf(l1 - m);
  float ssum = p0 + p1;
  for (int off = 32; off; off >>= 1) ssum += __shfl_xor(ssum, off);
  float o = 0.f;
  for (int j = 0; j < cnt; ++j) {
    float p = (j < 64) ? __shfl(p0, j) : __shfl(p1, j - 64);
    int ki = idx[j];
    o += p * vb[(long)ki * 256 + kvh * 64 + lane];
  }
  attn[(long)qi * 1024 + h * 64 + lane] = o / ssum;
}

// ---------------------------------------------------------------------------
extern "C" void kernel_launch(void* const* d_in, const int* in_sizes, int n_in,
                              void* d_out, int out_size, void* d_ws,
                              size_t ws_size, hipStream_t stream) {
  const float* hs   = (const float*)d_in[0];
  const float* cosb = (const float*)d_in[1];
  const float* sinb = (const float*)d_in[2];
  const float* Wq   = (const float*)d_in[3];
  const float* bq   = (const float*)d_in[4];
  const float* Wk   = (const float*)d_in[5];
  const float* bk   = (const float*)d_in[6];
  const float* Wv   = (const float*)d_in[7];
  const float* bv   = (const float*)d_in[8];
  const float* Wo   = (const float*)d_in[9];
  const float* Wik  = (const float*)d_in[10];
  const float* bik  = (const float*)d_in[11];
  const float* Wiw  = (const float*)d_in[12];
  const float* biw  = (const float*)d_in[13];
  float* out = (float*)d_out;

  float* ws = (float*)d_ws;
  float* qb   = ws;  ws += (long)SEQ * 1024;
  float* kb   = ws;  ws += (long)SEQ * 256;
  float* vb   = ws;  ws += (long)SEQ * 256;
  float* ikb  = ws;  ws += (long)SEQ * 64;
  float* wb   = ws;  ws += (long)SEQ * 16;
  float* attn = ws;  ws += (long)SEQ * 1024;
  int* tidx = (int*)ws;
  int* tcnt = tidx + (long)SEQ * TOPK;

  dim3 blk(256);
  gemm_f32<<<dim3(16, 32), blk, 0, stream>>>(hs, Wq, bq, qb, SEQ, 1024, 1024);
  gemm_f32<<<dim3(4, 32),  blk, 0, stream>>>(hs, Wk, bk, kb, SEQ, 256, 1024);
  gemm_f32<<<dim3(4, 32),  blk, 0, stream>>>(hs, Wv, bv, vb, SEQ, 256, 1024);
  gemm_f32<<<dim3(1, 32),  blk, 0, stream>>>(hs, Wik, bik, ikb, SEQ, 64, 1024);
  gemm_f32<<<dim3(1, 32),  blk, 0, stream>>>(hs, Wiw, biw, wb, SEQ, 16, 1024);

  int nrope = SEQ * (NH + NKV + 1) * 32;
  rope_kernel<<<(nrope + 255) / 256, blk, 0, stream>>>(qb, kb, ikb, cosb, sinb);

  indexer_topk<<<SEQ, blk, 0, stream>>>(qb, ikb, wb, tidx, tcnt);

  sparse_attn<<<dim3(NH, SEQ), dim3(64), 0, stream>>>(qb, kb, vb, tidx, tcnt,
                                                      attn);

  gemm_f32<<<dim3(16, 32), blk, 0, stream>>>(attn, Wo, nullptr, out, SEQ,
                                             1024, 1024);
}

// Round 4
// 847.810 us; speedup vs baseline: 1.7079x; 1.7079x over previous
//
#include <hip/hip_runtime.h>
#include <hip/hip_bf16.h>
#include <math.h>

#define SEQ   2048
#define HDIM  1024
#define NH    16
#define NKV   4
#define DHEAD 64
#define TOPK  128

// ---------------- f32 tiled GEMM: C[M,N] = A[M,K] @ W[N,K]^T + bias ----------
__global__ __launch_bounds__(256) void gemm_f32(
    const float* __restrict__ A, const float* __restrict__ W,
    const float* __restrict__ bias, float* __restrict__ C,
    int M, int N, int K) {
  constexpr int BM = 64, BN = 64, BK = 16;
  __shared__ float As[BK][BM + 4];   // +4 pad: float4-aligned rows, 2-way banks
  __shared__ float Ws[BK][BN + 4];
  int tid = threadIdx.x;
  int tx = tid & 15, ty = tid >> 4;
  int lr = tid >> 4, lc = tid & 15;
  int m0 = blockIdx.y * BM, n0 = blockIdx.x * BN;
  float acc[4][4] = {};
  for (int k0 = 0; k0 < K; k0 += BK) {
#pragma unroll
    for (int i = 0; i < 4; ++i) {
      int ar = m0 + lr + 16 * i;           // M==2048, always in-bounds
      As[lc][lr + 16 * i] = A[(long)ar * K + k0 + lc];
      int wr = n0 + lr + 16 * i;
      Ws[lc][lr + 16 * i] = (wr < N) ? W[(long)wr * K + k0 + lc] : 0.f;
    }
    __syncthreads();
#pragma unroll
    for (int kk = 0; kk < BK; ++kk) {
      float4 a4 = *(const float4*)&As[kk][ty * 4];
      float4 b4 = *(const float4*)&Ws[kk][tx * 4];
      float a[4] = {a4.x, a4.y, a4.z, a4.w};
      float b[4] = {b4.x, b4.y, b4.z, b4.w};
#pragma unroll
      for (int i = 0; i < 4; ++i)
#pragma unroll
        for (int j = 0; j < 4; ++j) acc[i][j] += a[i] * b[j];
    }
    __syncthreads();
  }
#pragma unroll
  for (int i = 0; i < 4; ++i) {
    int m = m0 + ty * 4 + i;
#pragma unroll
    for (int j = 0; j < 4; ++j) {
      int n = n0 + tx * 4 + j;
      if (n < N) C[(long)m * N + n] = acc[i][j] + (bias ? bias[n] : 0.f);
    }
  }
}

// ---------------- RoPE in place on q (S,NH,D), k (S,NKV,D), ik (S,D) --------
__global__ void rope_kernel(float* __restrict__ q, float* __restrict__ k,
                            float* __restrict__ ik,
                            const float* __restrict__ cosb,
                            const float* __restrict__ sinb) {
  int gid = blockIdx.x * 256 + threadIdx.x;
  const int NV = SEQ * (NH + NKV + 1);
  if (gid >= NV * 32) return;
  int p = gid & 31;
  int vec = gid >> 5;
  float* base;
  int s;
  if (vec < SEQ * NH) {
    s = vec / NH; int h = vec % NH;
    base = q + (long)s * 1024 + h * 64;
  } else if (vec < SEQ * (NH + NKV)) {
    int t = vec - SEQ * NH;
    s = t / NKV; int kh = t % NKV;
    base = k + (long)s * 256 + kh * 64;
  } else {
    s = vec - SEQ * (NH + NKV);
    base = ik + (long)s * 64;
  }
  float c = cosb[s * 64 + p], sn = sinb[s * 64 + p];
  float x1 = base[p], x2 = base[p + 32];
  base[p]      = x1 * c - x2 * sn;
  base[p + 32] = x2 * c + x1 * sn;
}

// ---- Phase A: causal-tiled indexer scores -> packed triangular buffer ------
// sc[q*(q+1)/2 + k] = sum_h relu(q[q,h,:].ik[k,:]) * w[q,h] * NH^-0.5,  k<=q
__global__ __launch_bounds__(256) void idx_scores(
    const float* __restrict__ qb, const float* __restrict__ ikb,
    const float* __restrict__ wb, float* __restrict__ sc) {
  int tk = blockIdx.x, tq = blockIdx.y;
  if (tk > tq) return;
  int q0 = tq * 64, k0 = tk * 64;
  __shared__ float As[64][68];     // [d][qrow]
  __shared__ float Bs[64][68];     // [d][krow]
  __shared__ float wls[64][17];    // [qrow][h]
  int tid = threadIdx.x;
  int lc = tid & 15, lr = tid >> 4;
  // stage ik tile once (h-independent)
#pragma unroll
  for (int c = 0; c < 4; ++c) {
    int d = c * 16 + lc;
#pragma unroll
    for (int i = 0; i < 4; ++i) {
      int kr = lr + 16 * i;
      Bs[d][kr] = ikb[(long)(k0 + kr) * 64 + d];
    }
  }
#pragma unroll
  for (int i = 0; i < 4; ++i)
    wls[lr + 16 * i][lc] = wb[(long)(q0 + lr + 16 * i) * 16 + lc] * 0.25f;
  int tx = tid & 15, ty = tid >> 4;
  float acc[4][4] = {};
  for (int h = 0; h < NH; ++h) {
    __syncthreads();               // As reuse fence (also fences Bs/wls at h=0)
#pragma unroll
    for (int c = 0; c < 4; ++c) {
      int d = c * 16 + lc;
#pragma unroll
      for (int i = 0; i < 4; ++i) {
        int qr = lr + 16 * i;
        As[d][qr] = qb[(long)(q0 + qr) * 1024 + h * 64 + d];
      }
    }
    __syncthreads();
    float dot[4][4] = {};
#pragma unroll
    for (int kk = 0; kk < 64; ++kk) {
      float4 a4 = *(const float4*)&As[kk][ty * 4];
      float4 b4 = *(const float4*)&Bs[kk][tx * 4];
      float a[4] = {a4.x, a4.y, a4.z, a4.w};
      float b[4] = {b4.x, b4.y, b4.z, b4.w};
#pragma unroll
      for (int i = 0; i < 4; ++i)
#pragma unroll
        for (int j = 0; j < 4; ++j) dot[i][j] += a[i] * b[j];
    }
    float wv[4];
#pragma unroll
    for (int i = 0; i < 4; ++i) wv[i] = wls[ty * 4 + i][h];
#pragma unroll
    for (int i = 0; i < 4; ++i)
#pragma unroll
      for (int j = 0; j < 4; ++j)
        acc[i][j] += fmaxf(dot[i][j], 0.f) * wv[i];
  }
#pragma unroll
  for (int i = 0; i < 4; ++i) {
    int q = q0 + ty * 4 + i;
    long base = (long)q * (q + 1) / 2;
#pragma unroll
    for (int j = 0; j < 4; ++j) {
      int k = k0 + tx * 4 + j;
      if (k <= q) sc[base + k] = acc[i][j];
    }
  }
}

// ---- Phase B: exact top-128 per row, one wave per row ----------------------
__device__ inline unsigned fkey(float f) {
  unsigned u = __float_as_uint(f);
  return (u & 0x80000000u) ? ~u : (u | 0x80000000u);
}

__global__ __launch_bounds__(64) void topk_rows(
    const float* __restrict__ sc, int* __restrict__ tidx,
    int* __restrict__ tcnt) {
  int qi = blockIdx.x;
  int lane = threadIdx.x;
  if (qi < TOPK) {                 // row length <= 128: all causal positions
    for (int i = lane; i <= qi; i += 64) tidx[(long)qi * TOPK + i] = i;
    if (lane == 0) tcnt[qi] = qi + 1;
    return;
  }
  const float* row = sc + (long)qi * (qi + 1) / 2;
  unsigned keys[32];
#pragma unroll
  for (int i = 0; i < 32; ++i) {
    int k = lane + 64 * i;
    keys[i] = (k <= qi) ? fkey(row[k] + 0.f) : 0u;   // +0: kill -0.0
  }
  unsigned lo = 0u, hi = 0xFFFFFFFEu;
  while (lo < hi) {
    unsigned mid = lo + ((hi - lo + 1) >> 1);
    int cnt = 0;
#pragma unroll
    for (int i = 0; i < 32; ++i) cnt += (keys[i] >= mid) ? 1 : 0;
    for (int off = 32; off; off >>= 1) cnt += __shfl_xor(cnt, off);
    if (cnt >= TOPK) lo = mid; else hi = mid - 1;
  }
  unsigned T = lo;
  __shared__ int c1;
  if (lane == 0) c1 = 0;
  __syncthreads();
#pragma unroll
  for (int i = 0; i < 32; ++i) {
    if (keys[i] > T) {
      int pos = atomicAdd(&c1, 1);
      tidx[(long)qi * TOPK + pos] = lane + 64 * i;
    }
  }
  __syncthreads();
  int c = c1;
  for (int i = 0; i < 32 && c < TOPK; ++i) {   // ==T: ascending index fill
    unsigned long long m = __ballot(keys[i] == T);
    while (m && c < TOPK) {
      int l = __ffsll(m) - 1;
      m &= m - 1;
      if (lane == 0) tidx[(long)qi * TOPK + c] = 64 * i + l;
      ++c;
    }
  }
  if (lane == 0) tcnt[qi] = TOPK;
}

// ---- sparse attention: one block per (q, kvh); 4 waves = 4 heads share K/V -
__global__ __launch_bounds__(256) void sparse_attn(
    const float* __restrict__ qb, const float* __restrict__ kb,
    const float* __restrict__ vb, const int* __restrict__ tidx,
    const int* __restrict__ tcnt, float* __restrict__ attn) {
  int kvh = blockIdx.x;
  int qi  = blockIdx.y;
  int tid = threadIdx.x, lane = tid & 63, w = tid >> 6;
  int h = kvh * 4 + w;
  int cnt = tcnt[qi];
  __shared__ int   idxs[128];
  __shared__ float Ks[128][65];     // stride 65: conflict-free both phases
  __shared__ float Vs[128][65];
  __shared__ float qs[4][64];
  __shared__ float ps[4][128];
  if (tid < 128) idxs[tid] = (tid < cnt) ? tidx[(long)qi * TOPK + tid] : 0;
  qs[w][lane] = qb[(long)qi * 1024 + h * 64 + lane];
  __syncthreads();
  {
    int j = tid >> 1, hf = tid & 1;     // 2 threads per K/V row
    if (j < cnt) {
      int ki = idxs[j];
      const float4* kr = (const float4*)(kb + (long)ki * 256 + kvh * 64 + hf * 32);
      const float4* vr = (const float4*)(vb + (long)ki * 256 + kvh * 64 + hf * 32);
#pragma unroll
      for (int c = 0; c < 8; ++c) {
        float4 kk = kr[c], vv = vr[c];
        int d0 = hf * 32 + c * 4;
        Ks[j][d0 + 0] = kk.x; Ks[j][d0 + 1] = kk.y;
        Ks[j][d0 + 2] = kk.z; Ks[j][d0 + 3] = kk.w;
        Vs[j][d0 + 0] = vv.x; Vs[j][d0 + 1] = vv.y;
        Vs[j][d0 + 2] = vv.z; Vs[j][d0 + 3] = vv.w;
      }
    }
  }
  __syncthreads();
  float l0 = -INFINITY, l1 = -INFINITY;
  if (lane < cnt) {
    float d = 0.f;
#pragma unroll
    for (int dd = 0; dd < 64; ++dd) d += qs[w][dd] * Ks[lane][dd];
    l0 = d * 0.125f;
  }
  if (lane + 64 < cnt) {
    float d = 0.f;
#pragma unroll
    for (int dd = 0; dd < 64; ++dd) d += qs[w][dd] * Ks[lane + 64][dd];
    l1 = d * 0.125f;
  }
  float m = fmaxf(l0, l1);
  for (int off = 32; off; off >>= 1) m = fmaxf(m, __shfl_xor(m, off));
  float p0 = expf(l0 - m), p1 = expf(l1 - m);
  float ssum = p0 + p1;
  for (int off = 32; off; off >>= 1) ssum += __shfl_xor(ssum, off);
  ps[w][lane] = p0;
  ps[w][lane + 64] = p1;
  __syncthreads();
  float o = 0.f;
  for (int j = 0; j < cnt; ++j) o += ps[w][j] * Vs[j][lane];
  attn[(long)qi * 1024 + h * 64 + lane] = o / ssum;
}

// ---------------------------------------------------------------------------
extern "C" void kernel_launch(void* const* d_in, const int* in_sizes, int n_in,
                              void* d_out, int out_size, void* d_ws,
                              size_t ws_size, hipStream_t stream) {
  const float* hs   = (const float*)d_in[0];
  const float* cosb = (const float*)d_in[1];
  const float* sinb = (const float*)d_in[2];
  const float* Wq   = (const float*)d_in[3];
  const float* bq   = (const float*)d_in[4];
  const float* Wk   = (const float*)d_in[5];
  const float* bk   = (const float*)d_in[6];
  const float* Wv   = (const float*)d_in[7];
  const float* bv   = (const float*)d_in[8];
  const float* Wo   = (const float*)d_in[9];
  const float* Wik  = (const float*)d_in[10];
  const float* bik  = (const float*)d_in[11];
  const float* Wiw  = (const float*)d_in[12];
  const float* biw  = (const float*)d_in[13];
  float* out = (float*)d_out;

  float* ws = (float*)d_ws;
  float* qb   = ws;  ws += (long)SEQ * 1024;
  float* kb   = ws;  ws += (long)SEQ * 256;
  float* vb   = ws;  ws += (long)SEQ * 256;
  float* ikb  = ws;  ws += (long)SEQ * 64;
  float* wb   = ws;  ws += (long)SEQ * 16;
  int* tidx   = (int*)ws;  ws += (long)SEQ * TOPK;
  int* tcnt   = (int*)ws;  ws += SEQ;
  float* scores = ws;                 // packed triangular: S*(S+1)/2 floats
  float* attn   = ws;                 // aliased: scores dead before attn write

  dim3 blk(256);
  gemm_f32<<<dim3(16, 32), blk, 0, stream>>>(hs, Wq, bq, qb, SEQ, 1024, 1024);
  gemm_f32<<<dim3(4, 32),  blk, 0, stream>>>(hs, Wk, bk, kb, SEQ, 256, 1024);
  gemm_f32<<<dim3(4, 32),  blk, 0, stream>>>(hs, Wv, bv, vb, SEQ, 256, 1024);
  gemm_f32<<<dim3(1, 32),  blk, 0, stream>>>(hs, Wik, bik, ikb, SEQ, 64, 1024);
  gemm_f32<<<dim3(1, 32),  blk, 0, stream>>>(hs, Wiw, biw, wb, SEQ, 16, 1024);

  int nrope = SEQ * (NH + NKV + 1) * 32;
  rope_kernel<<<(nrope + 255) / 256, blk, 0, stream>>>(qb, kb, ikb, cosb, sinb);

  idx_scores<<<dim3(32, 32), blk, 0, stream>>>(qb, ikb, wb, scores);
  topk_rows<<<SEQ, dim3(64), 0, stream>>>(scores, tidx, tcnt);

  sparse_attn<<<dim3(NKV, SEQ), blk, 0, stream>>>(qb, kb, vb, tidx, tcnt,
                                                  attn);

  gemm_f32<<<dim3(16, 32), blk, 0, stream>>>(attn, Wo, nullptr, out, SEQ,
                                             1024, 1024);
}

// Round 5
// 403.839 us; speedup vs baseline: 3.5854x; 2.0994x over previous
//
#include <hip/hip_runtime.h>
#include <hip/hip_bf16.h>
#include <math.h>

#define SEQ   2048
#define HDIM  1024
#define NH    16
#define NKV   4
#define DHEAD 64
#define TOPK  128

typedef __attribute__((ext_vector_type(8))) short short8;
typedef __attribute__((ext_vector_type(4))) float f32x4;

__device__ inline short f2bf_bits(float x) {          // RTN-even f32 -> bf16
  unsigned u = __float_as_uint(x);
  unsigned r = (u + 0x7FFFu + ((u >> 16) & 1u)) >> 16;
  return (short)r;
}
__device__ inline float bf2f(short s) {
  return __uint_as_float(((unsigned)(unsigned short)s) << 16);
}

// ---- split-precision MFMA GEMM for q/ik/w projections (indexer-sensitive) --
// C = hs @ Wx^T + b, computed as (hi+lo)x(hi+lo) with 3 MFMA products.
// N-concat tiles: 0-15 -> Wq(1024), 16 -> Wik(64), 17 -> Wiw(16, padded)
__global__ __launch_bounds__(256) void mfma_qiw(
    const float* __restrict__ hs, const float* __restrict__ Wq,
    const float* __restrict__ bq, const float* __restrict__ Wik,
    const float* __restrict__ bik, const float* __restrict__ Wiw,
    const float* __restrict__ biw, float* __restrict__ qb,
    float* __restrict__ ikb, float* __restrict__ wb) {
  constexpr int K = 1024;
  int nt = blockIdx.x;
  int m0 = blockIdx.y * 64;
  const float* W; const float* bias; int Nvalid;
  if (nt < 16)       { W = Wq + (long)nt * 64 * K; bias = bq + nt * 64; Nvalid = 64; }
  else if (nt == 16) { W = Wik; bias = bik; Nvalid = 64; }
  else               { W = Wiw; bias = biw; Nvalid = 16; }

  __shared__ short Ahi[64 * 32] __attribute__((aligned(16)));
  __shared__ short Alo[64 * 32] __attribute__((aligned(16)));
  __shared__ short Bhi[64 * 32] __attribute__((aligned(16)));
  __shared__ short Blo[64 * 32] __attribute__((aligned(16)));

  int tid = threadIdx.x;
  int lane = tid & 63, wid = tid >> 6;
  int wm = (wid >> 1) * 32, wn = (wid & 1) * 32;
  int srow = tid >> 2, ksp = tid & 3;
  int klog = ksp ^ (srow & 3);                 // XOR-swizzle (4-way -> ~free)
  int lr = lane & 15, kg = lane >> 4;

  f32x4 acc[2][2] = {};
  for (int k0 = 0; k0 < K; k0 += 32) {
    const float* asrc = hs + (long)(m0 + srow) * K + k0 + klog * 8;
    const float* wsrc = W + (long)srow * K + k0 + klog * 8;
    bool wok = srow < Nvalid;
    short8 ah, al, wh, wl;
#pragma unroll
    for (int i = 0; i < 8; ++i) {
      float a = asrc[i];
      short h = f2bf_bits(a); ah[i] = h; al[i] = f2bf_bits(a - bf2f(h));
      float w = wok ? wsrc[i] : 0.f;
      short g = f2bf_bits(w); wh[i] = g; wl[i] = f2bf_bits(w - bf2f(g));
    }
    __syncthreads();
    int sl = srow * 32 + ksp * 8;
    *(short8*)&Ahi[sl] = ah; *(short8*)&Alo[sl] = al;
    *(short8*)&Bhi[sl] = wh; *(short8*)&Blo[sl] = wl;
    __syncthreads();
#pragma unroll
    for (int fi = 0; fi < 2; ++fi) {
      int ar = wm + fi * 16 + lr;
      int ap = ar * 32 + (kg ^ (ar & 3)) * 8;
      short8 a_h = *(short8*)&Ahi[ap];
      short8 a_l = *(short8*)&Alo[ap];
#pragma unroll
      for (int fj = 0; fj < 2; ++fj) {
        int br = wn + fj * 16 + lr;
        int bp = br * 32 + (kg ^ (br & 3)) * 8;
        short8 b_h = *(short8*)&Bhi[bp];
        short8 b_l = *(short8*)&Blo[bp];
        acc[fi][fj] = __builtin_amdgcn_mfma_f32_16x16x32_bf16(a_h, b_h, acc[fi][fj], 0, 0, 0);
        acc[fi][fj] = __builtin_amdgcn_mfma_f32_16x16x32_bf16(a_h, b_l, acc[fi][fj], 0, 0, 0);
        acc[fi][fj] = __builtin_amdgcn_mfma_f32_16x16x32_bf16(a_l, b_h, acc[fi][fj], 0, 0, 0);
      }
    }
  }
  int rg = lane >> 4;
#pragma unroll
  for (int fi = 0; fi < 2; ++fi)
#pragma unroll
    for (int fj = 0; fj < 2; ++fj)
#pragma unroll
      for (int r = 0; r < 4; ++r) {
        int gm = m0 + wm + fi * 16 + rg * 4 + r;
        int nc = wn + fj * 16 + lr;
        float v = acc[fi][fj][r];
        if (nt < 16)        qb[(long)gm * 1024 + nt * 64 + nc] = v + bias[nc];
        else if (nt == 16)  ikb[(long)gm * 64 + nc] = v + bias[nc];
        else if (nc < 16)   wb[(long)gm * 16 + nc] = v + bias[nc];
      }
}

// ---- plain bf16 MFMA GEMM: out[m, 0..N) = A[m,:] @ W[n,:] + bias ----------
__global__ __launch_bounds__(256) void mfma_plain(
    const float* __restrict__ A, const float* __restrict__ W,
    const float* __restrict__ bias, float* __restrict__ out, int N) {
  constexpr int K = 1024;
  int n0 = blockIdx.x * 64;
  int m0 = blockIdx.y * 64;
  __shared__ short As[64 * 32] __attribute__((aligned(16)));
  __shared__ short Bs[64 * 32] __attribute__((aligned(16)));
  int tid = threadIdx.x;
  int lane = tid & 63, wid = tid >> 6;
  int wm = (wid >> 1) * 32, wn = (wid & 1) * 32;
  int srow = tid >> 2, ksp = tid & 3;
  int klog = ksp ^ (srow & 3);
  int lr = lane & 15, kg = lane >> 4;

  f32x4 acc[2][2] = {};
  for (int k0 = 0; k0 < K; k0 += 32) {
    const float* asrc = A + (long)(m0 + srow) * K + k0 + klog * 8;
    const float* wsrc = W + (long)(n0 + srow) * K + k0 + klog * 8;
    short8 av, wv;
#pragma unroll
    for (int i = 0; i < 8; ++i) {
      av[i] = f2bf_bits(asrc[i]);
      wv[i] = f2bf_bits(wsrc[i]);
    }
    __syncthreads();
    int sl = srow * 32 + ksp * 8;
    *(short8*)&As[sl] = av; *(short8*)&Bs[sl] = wv;
    __syncthreads();
#pragma unroll
    for (int fi = 0; fi < 2; ++fi) {
      int ar = wm + fi * 16 + lr;
      short8 a = *(short8*)&As[ar * 32 + (kg ^ (ar & 3)) * 8];
#pragma unroll
      for (int fj = 0; fj < 2; ++fj) {
        int br = wn + fj * 16 + lr;
        short8 b = *(short8*)&Bs[br * 32 + (kg ^ (br & 3)) * 8];
        acc[fi][fj] = __builtin_amdgcn_mfma_f32_16x16x32_bf16(a, b, acc[fi][fj], 0, 0, 0);
      }
    }
  }
  int rg = lane >> 4;
#pragma unroll
  for (int fi = 0; fi < 2; ++fi)
#pragma unroll
    for (int fj = 0; fj < 2; ++fj)
#pragma unroll
      for (int r = 0; r < 4; ++r) {
        int gm = m0 + wm + fi * 16 + rg * 4 + r;
        int gn = n0 + wn + fj * 16 + lr;
        out[(long)gm * N + gn] = acc[fi][fj][r] + (bias ? bias[gn] : 0.f);
      }
}

// ---------------- RoPE in place on q (S,NH,D), k (S,NKV,D), ik (S,D) --------
__global__ void rope_kernel(float* __restrict__ q, float* __restrict__ k,
                            float* __restrict__ ik,
                            const float* __restrict__ cosb,
                            const float* __restrict__ sinb) {
  int gid = blockIdx.x * 256 + threadIdx.x;
  const int NV = SEQ * (NH + NKV + 1);
  if (gid >= NV * 32) return;
  int p = gid & 31;
  int vec = gid >> 5;
  float* base;
  int s;
  if (vec < SEQ * NH) {
    s = vec / NH; int h = vec % NH;
    base = q + (long)s * 1024 + h * 64;
  } else if (vec < SEQ * (NH + NKV)) {
    int t = vec - SEQ * NH;
    s = t / NKV; int kh = t % NKV;
    base = k + (long)s * 256 + kh * 64;
  } else {
    s = vec - SEQ * (NH + NKV);
    base = ik + (long)s * 64;
  }
  float c = cosb[s * 64 + p], sn = sinb[s * 64 + p];
  float x1 = base[p], x2 = base[p + 32];
  base[p]      = x1 * c - x2 * sn;
  base[p + 32] = x2 * c + x1 * sn;
}

// ---- indexer scores (f32, top-k-sensitive) -> packed triangular buffer -----
__global__ __launch_bounds__(256) void idx_scores(
    const float* __restrict__ qb, const float* __restrict__ ikb,
    const float* __restrict__ wb, float* __restrict__ sc) {
  int b = blockIdx.x;                         // 0..527 triangular
  int tq = (int)((sqrtf(8.f * b + 1.f) - 1.f) * 0.5f);
  while ((tq * (tq + 1)) / 2 > b) --tq;
  while (((tq + 1) * (tq + 2)) / 2 <= b) ++tq;
  int tk = b - (tq * (tq + 1)) / 2;
  int q0 = tq * 64, k0 = tk * 64;
  __shared__ float As[64][68];     // [d][qrow]
  __shared__ float Bs[64][68];     // [d][krow]
  int tid = threadIdx.x;
  int lc = tid & 15, lr = tid >> 4;
  int tx = lc, ty = lr;
#pragma unroll
  for (int c = 0; c < 4; ++c) {
    int d = c * 16 + lc;
#pragma unroll
    for (int i = 0; i < 4; ++i)
      Bs[d][lr + 16 * i] = ikb[(long)(k0 + lr + 16 * i) * 64 + d];
  }
  float pf[16];
#pragma unroll
  for (int c = 0; c < 4; ++c)
#pragma unroll
    for (int i = 0; i < 4; ++i)
      pf[c * 4 + i] = qb[(long)(q0 + lr + 16 * i) * 1024 + c * 16 + lc];
  float acc[4][4] = {};
  for (int h = 0; h < NH; ++h) {
    __syncthreads();                         // prior compute done
#pragma unroll
    for (int c = 0; c < 4; ++c)
#pragma unroll
      for (int i = 0; i < 4; ++i)
        As[c * 16 + lc][lr + 16 * i] = pf[c * 4 + i];
    if (h < NH - 1) {
#pragma unroll
      for (int c = 0; c < 4; ++c)
#pragma unroll
        for (int i = 0; i < 4; ++i)
          pf[c * 4 + i] =
              qb[(long)(q0 + lr + 16 * i) * 1024 + (h + 1) * 64 + c * 16 + lc];
    }
    __syncthreads();
    float wv[4];
#pragma unroll
    for (int i = 0; i < 4; ++i)
      wv[i] = wb[(long)(q0 + ty * 4 + i) * 16 + h] * 0.25f;
    float dot[4][4] = {};
#pragma unroll
    for (int kk = 0; kk < 64; ++kk) {
      float4 a4 = *(const float4*)&As[kk][ty * 4];
      float4 b4 = *(const float4*)&Bs[kk][tx * 4];
      float a[4] = {a4.x, a4.y, a4.z, a4.w};
      float bb[4] = {b4.x, b4.y, b4.z, b4.w};
#pragma unroll
      for (int i = 0; i < 4; ++i)
#pragma unroll
        for (int j = 0; j < 4; ++j) dot[i][j] += a[i] * bb[j];
    }
#pragma unroll
    for (int i = 0; i < 4; ++i)
#pragma unroll
      for (int j = 0; j < 4; ++j)
        acc[i][j] += fmaxf(dot[i][j], 0.f) * wv[i];
  }
#pragma unroll
  for (int i = 0; i < 4; ++i) {
    int q = q0 + ty * 4 + i;
    long base = (long)q * (q + 1) / 2;
#pragma unroll
    for (int j = 0; j < 4; ++j) {
      int k = k0 + tx * 4 + j;
      if (k <= q) sc[base + k] = acc[i][j];
    }
  }
}

// ---- exact top-128 per row, one wave per row -------------------------------
__device__ inline unsigned fkey(float f) {
  unsigned u = __float_as_uint(f);
  return (u & 0x80000000u) ? ~u : (u | 0x80000000u);
}

__global__ __launch_bounds__(64) void topk_rows(
    const float* __restrict__ sc, int* __restrict__ tidx,
    int* __restrict__ tcnt) {
  int qi = blockIdx.x;
  int lane = threadIdx.x;
  if (qi < TOPK) {
    for (int i = lane; i <= qi; i += 64) tidx[(long)qi * TOPK + i] = i;
    if (lane == 0) tcnt[qi] = qi + 1;
    return;
  }
  const float* row = sc + (long)qi * (qi + 1) / 2;
  unsigned keys[32];
#pragma unroll
  for (int i = 0; i < 32; ++i) {
    int k = lane + 64 * i;
    keys[i] = (k <= qi) ? fkey(row[k] + 0.f) : 0u;
  }
  unsigned lo = 0u, hi = 0xFFFFFFFEu;
  while (lo < hi) {
    unsigned mid = lo + ((hi - lo + 1) >> 1);
    int cnt = 0;
#pragma unroll
    for (int i = 0; i < 32; ++i) cnt += (keys[i] >= mid) ? 1 : 0;
    for (int off = 32; off; off >>= 1) cnt += __shfl_xor(cnt, off);
    if (cnt >= TOPK) lo = mid; else hi = mid - 1;
  }
  unsigned T = lo;
  __shared__ int c1;
  if (lane == 0) c1 = 0;
  __syncthreads();
#pragma unroll
  for (int i = 0; i < 32; ++i) {
    if (keys[i] > T) {
      int pos = atomicAdd(&c1, 1);
      tidx[(long)qi * TOPK + pos] = lane + 64 * i;
    }
  }
  __syncthreads();
  int c = c1;
  for (int i = 0; i < 32 && c < TOPK; ++i) {
    unsigned long long m = __ballot(keys[i] == T);
    while (m && c < TOPK) {
      int l = __ffsll(m) - 1;
      m &= m - 1;
      if (lane == 0) tidx[(long)qi * TOPK + c] = 64 * i + l;
      ++c;
    }
  }
  if (lane == 0) tcnt[qi] = TOPK;
}

// ---- sparse attention: one block per (q, kvh); 4 waves = 4 heads share K/V -
__global__ __launch_bounds__(256) void sparse_attn(
    const float* __restrict__ qb, const float* __restrict__ kb,
    const float* __restrict__ vb, const int* __restrict__ tidx,
    const int* __restrict__ tcnt, float* __restrict__ attn) {
  int kvh = blockIdx.x;
  int qi  = blockIdx.y;
  int tid = threadIdx.x, lane = tid & 63, w = tid >> 6;
  int h = kvh * 4 + w;
  int cnt = tcnt[qi];
  __shared__ int   idxs[128];
  __shared__ float Ks[128][65];
  __shared__ float Vs[128][65];
  __shared__ float qs[4][64];
  __shared__ float ps[4][128];
  if (tid < 128) idxs[tid] = (tid < cnt) ? tidx[(long)qi * TOPK + tid] : 0;
  qs[w][lane] = qb[(long)qi * 1024 + h * 64 + lane];
  __syncthreads();
  {
    int j = tid >> 1, hf = tid & 1;
    if (j < cnt) {
      int ki = idxs[j];
      const float4* kr = (const float4*)(kb + (long)ki * 256 + kvh * 64 + hf * 32);
      const float4* vr = (const float4*)(vb + (long)ki * 256 + kvh * 64 + hf * 32);
#pragma unroll
      for (int c = 0; c < 8; ++c) {
        float4 kk = kr[c], vv = vr[c];
        int d0 = hf * 32 + c * 4;
        Ks[j][d0 + 0] = kk.x; Ks[j][d0 + 1] = kk.y;
        Ks[j][d0 + 2] = kk.z; Ks[j][d0 + 3] = kk.w;
        Vs[j][d0 + 0] = vv.x; Vs[j][d0 + 1] = vv.y;
        Vs[j][d0 + 2] = vv.z; Vs[j][d0 + 3] = vv.w;
      }
    }
  }
  __syncthreads();
  float l0 = -INFINITY, l1 = -INFINITY;
  if (lane < cnt) {
    float d = 0.f;
#pragma unroll
    for (int dd = 0; dd < 64; ++dd) d += qs[w][dd] * Ks[lane][dd];
    l0 = d * 0.125f;
  }
  if (lane + 64 < cnt) {
    float d = 0.f;
#pragma unroll
    for (int dd = 0; dd < 64; ++dd) d += qs[w][dd] * Ks[lane + 64][dd];
    l1 = d * 0.125f;
  }
  float m = fmaxf(l0, l1);
  for (int off = 32; off; off >>= 1) m = fmaxf(m, __shfl_xor(m, off));
  float p0 = expf(l0 - m), p1 = expf(l1 - m);
  float ssum = p0 + p1;
  for (int off = 32; off; off >>= 1) ssum += __shfl_xor(ssum, off);
  ps[w][lane] = p0;
  ps[w][lane + 64] = p1;
  __syncthreads();
  float o = 0.f;
  for (int j = 0; j < cnt; ++j) o += ps[w][j] * Vs[j][lane];
  attn[(long)qi * 1024 + h * 64 + lane] = o / ssum;
}

// ---------------------------------------------------------------------------
extern "C" void kernel_launch(void* const* d_in, const int* in_sizes, int n_in,
                              void* d_out, int out_size, void* d_ws,
                              size_t ws_size, hipStream_t stream) {
  const float* hs   = (const float*)d_in[0];
  const float* cosb = (const float*)d_in[1];
  const float* sinb = (const float*)d_in[2];
  const float* Wq   = (const float*)d_in[3];
  const float* bq   = (const float*)d_in[4];
  const float* Wk   = (const float*)d_in[5];
  const float* bk   = (const float*)d_in[6];
  const float* Wv   = (const float*)d_in[7];
  const float* bv   = (const float*)d_in[8];
  const float* Wo   = (const float*)d_in[9];
  const float* Wik  = (const float*)d_in[10];
  const float* bik  = (const float*)d_in[11];
  const float* Wiw  = (const float*)d_in[12];
  const float* biw  = (const float*)d_in[13];
  float* out = (float*)d_out;

  float* ws = (float*)d_ws;
  float* qb   = ws;  ws += (long)SEQ * 1024;
  float* kb   = ws;  ws += (long)SEQ * 256;
  float* vb   = ws;  ws += (long)SEQ * 256;
  float* ikb  = ws;  ws += (long)SEQ * 64;
  float* wb   = ws;  ws += (long)SEQ * 16;
  int* tidx   = (int*)ws;  ws += (long)SEQ * TOPK;
  int* tcnt   = (int*)ws;  ws += SEQ;
  float* scores = ws;                 // packed triangular: S*(S+1)/2 floats
  float* attn   = ws;                 // aliased: scores dead before attn write

  dim3 blk(256);
  mfma_qiw<<<dim3(18, 32), blk, 0, stream>>>(hs, Wq, bq, Wik, bik, Wiw, biw,
                                             qb, ikb, wb);
  mfma_plain<<<dim3(4, 32), blk, 0, stream>>>(hs, Wk, bk, kb, 256);
  mfma_plain<<<dim3(4, 32), blk, 0, stream>>>(hs, Wv, bv, vb, 256);

  int nrope = SEQ * (NH + NKV + 1) * 32;
  rope_kernel<<<(nrope + 255) / 256, blk, 0, stream>>>(qb, kb, ikb, cosb, sinb);

  idx_scores<<<528, blk, 0, stream>>>(qb, ikb, wb, scores);
  topk_rows<<<SEQ, dim3(64), 0, stream>>>(scores, tidx, tcnt);

  sparse_attn<<<dim3(NKV, SEQ), blk, 0, stream>>>(qb, kb, vb, tidx, tcnt,
                                                  attn);

  mfma_plain<<<dim3(16, 32), blk, 0, stream>>>(attn, Wo, nullptr, out, 1024);
}